// Round 11
// baseline (178.389 us; speedup 1.0000x reference)
//
#include <hip/hip_runtime.h>
#include <hip/hip_bf16.h>
#include <cstdint>
#include <cstddef>

#define N_TOK 65536
#define DIM 128
#define HID 256
#define NE 32
#define TOPK 2

typedef __bf16 bf16x8 __attribute__((ext_vector_type(8)));
typedef float f32x4 __attribute__((ext_vector_type(4)));
typedef unsigned uint4v __attribute__((ext_vector_type(4)));

// LDS address with XOR swizzle: inject c's low 2 bits into bank bits 5-6.
#define LDSA(c, row, byte) ((((c) * 1024 + (row) * 16 + (byte))) ^ ((((c) & 3) << 5)))

typedef const __attribute__((address_space(1))) unsigned int gas_uint;
typedef __attribute__((address_space(3))) unsigned int las_uint;

__device__ __forceinline__ unsigned short f2bf(float f) {
  unsigned u = __builtin_bit_cast(unsigned, f);
  u += 0x7fffu + ((u >> 16) & 1u);   // round-to-nearest-even
  return (unsigned short)(u >> 16);
}
__device__ __forceinline__ float bf2f(unsigned s) {
  return __builtin_bit_cast(float, s << 16);
}
// truncation split: f = hi + lo + O(2^-14 |f|); packs two values' shorts into one uint.
__device__ __forceinline__ uint2 split2(float f0, float f1) {
  unsigned u0 = __builtin_bit_cast(unsigned, f0);
  unsigned u1 = __builtin_bit_cast(unsigned, f1);
  unsigned hi = (u0 >> 16) | (u1 & 0xffff0000u);
  float r0 = f0 - __builtin_bit_cast(float, u0 & 0xffff0000u);
  float r1 = f1 - __builtin_bit_cast(float, u1 & 0xffff0000u);
  unsigned lo = (__builtin_bit_cast(unsigned, r0) >> 16) |
                (__builtin_bit_cast(unsigned, r1) & 0xffff0000u);
  uint2 ret; ret.x = hi; ret.y = lo;
  return ret;
}

// ---------------- fallback-only: zero out ----------------
__global__ void k_zero_out(float* __restrict__ out) {
  int t = blockIdx.x * 256 + threadIdx.x;
  float4 z = make_float4(0.f, 0.f, 0.f, 0.f);
  float4* o4 = (float4*)out;
  o4[t] = z;
  o4[t + 1048576] = z;
}

// ---------------- k_front: router (+inline fp64 fix, hist, xb) + weight transpose ----------------
// blocks 0..1023:    router, 64 tokens each. blocks 1024..1535: W1/W2 bf16 transpose.
// Router uses SWAPPED mfma operands (Wr as A, x as B) so C is [expert][token]:
// each lane holds 8 expert-logits for ONE token -> top-3 is 8 serial compares +
// 2 shfl-merge steps instead of 12 butterfly passes. Logit values bit-identical.
__global__ __launch_bounds__(256, 3) void k_front(
    const float* __restrict__ x, const float* __restrict__ W1,
    const float* __restrict__ W2, const float* __restrict__ Wr,
    const float* __restrict__ br,
    int* __restrict__ top_idx, float* __restrict__ top_val,
    unsigned short* __restrict__ xb,
    unsigned short* __restrict__ w1t, unsigned short* __restrict__ w2t,
    int* __restrict__ histbuf, float* __restrict__ impbuf) {
  int b = blockIdx.x;
  int t = threadIdx.x;

  if (b >= 1024) {
    // ---------- weight transpose ----------
    int bb = b - 1024;
    const float* in;
    unsigned short* outp;
    int K, r0, c0;
    bool isW1;
    if (bb < 256) {
      int e = bb >> 3, tt = bb & 7;
      in = W1 + (size_t)e * DIM * HID;   // [d][h] 128x256
      outp = w1t + (size_t)e * DIM * HID;
      K = HID;
      r0 = (tt >> 2) * 64; c0 = (tt & 3) * 64;
      isW1 = true;
    } else {
      bb -= 256;
      int e = bb >> 3, tt = bb & 7;
      in = W2 + (size_t)e * HID * DIM;   // [h][d] 256x128
      outp = w2t + (size_t)e * HID * DIM;
      K = DIM;
      r0 = (tt >> 1) * 64; c0 = (tt & 1) * 64;
      isW1 = false;
    }
    __shared__ float tile[64][65];
    int r = t >> 2, cs = (t & 3) * 16;
    const float* src = in + (size_t)(r0 + r) * K + c0 + cs;
#pragma unroll
    for (int j = 0; j < 4; ++j) {
      float4 v = *(const float4*)(src + j * 4);
      tile[r][cs + j * 4 + 0] = v.x;
      tile[r][cs + j * 4 + 1] = v.y;
      tile[r][cs + j * 4 + 2] = v.z;
      tile[r][cs + j * 4 + 3] = v.w;
    }
    __syncthreads();
#pragma unroll
    for (int p = 0; p < 2; ++p) {
      int orow = p * 32 + (t >> 3);
      int oc8 = (t & 7) * 8;
      int rr = r0 + oc8;
      unsigned pk[4];
#pragma unroll
      for (int q = 0; q < 4; ++q) {
        unsigned lo = f2bf(tile[oc8 + 2 * q][orow]);
        unsigned hi = f2bf(tile[oc8 + 2 * q + 1][orow]);
        pk[q] = lo | (hi << 16);
      }
      uint4 u;
      u.x = pk[0]; u.y = pk[1]; u.z = pk[2]; u.w = pk[3];
      int h = c0 + orow;
      int hp = isW1 ? ((h & ~63) | ((h & 3) << 4) | ((h & 63) >> 2))
                    : ((h & ~31) | ((h & 1) << 4) | ((h & 31) >> 1));
      size_t addr = (size_t)(rr >> 5) * (K * 32) + (size_t)hp * 32 + (rr & 31);
      *(uint4*)(outp + addr) = u;
    }
    return;
  }

  // ---------- router: 64 tokens/block ----------
  __shared__ int hc[NE];
  __shared__ float hf[NE];
  __shared__ int slist[64];
  __shared__ int scount;
  if (t < NE) { hc[t] = 0; hf[t] = 0.f; }
  if (t == 0) scount = 0;
  __syncthreads();

  int w = t >> 6, l = t & 63, quad = l >> 4, l15 = l & 15;
  int tok0 = b * 64 + w * 16;

  // Build Wr fragments (hi/lo split) directly from Wr (L1/L2-hot 16 KB table).
  bf16x8 bfr[2][2][4];
#pragma unroll
  for (int nt = 0; nt < 2; ++nt)
#pragma unroll
    for (int kc = 0; kc < 4; ++kc) {
      unsigned hiw[4], low[4];
#pragma unroll
      for (int jp = 0; jp < 4; ++jp) {
        int k0 = kc * 32 + quad * 8 + jp * 2;
        int e = nt * 16 + l15;
        float w0 = Wr[k0 * NE + e];
        float w1v = Wr[(k0 + 1) * NE + e];
        uint2 s = split2(w0, w1v);
        hiw[jp] = s.x; low[jp] = s.y;
      }
      uint4v h4, l4;
      h4[0] = hiw[0]; h4[1] = hiw[1]; h4[2] = hiw[2]; h4[3] = hiw[3];
      l4[0] = low[0]; l4[1] = low[1]; l4[2] = low[2]; l4[3] = low[3];
      bfr[0][nt][kc] = __builtin_bit_cast(bf16x8, h4);
      bfr[1][nt][kc] = __builtin_bit_cast(bf16x8, l4);
    }

  f32x4 acc[2];
#pragma unroll
  for (int a = 0; a < 2; ++a) {
    f32x4 z = {0.f, 0.f, 0.f, 0.f};
    acc[a] = z;
  }

  {
    const float* xp = x + (size_t)(tok0 + l15) * DIM + quad * 8;
    float4 va[4][2];
#pragma unroll
    for (int kc = 0; kc < 4; ++kc) {
      const float4* p = (const float4*)(xp + kc * 32);
      va[kc][0] = p[0];
      va[kc][1] = p[1];
    }
    // bf16 row-major copy of x for k_expert's gather
    unsigned short* xrow = xb + (size_t)(tok0 + l15) * DIM + quad * 8;
#pragma unroll
    for (int kc = 0; kc < 4; ++kc) {
      uint4 u;
      u.x = (unsigned)f2bf(va[kc][0].x) | ((unsigned)f2bf(va[kc][0].y) << 16);
      u.y = (unsigned)f2bf(va[kc][0].z) | ((unsigned)f2bf(va[kc][0].w) << 16);
      u.z = (unsigned)f2bf(va[kc][1].x) | ((unsigned)f2bf(va[kc][1].y) << 16);
      u.w = (unsigned)f2bf(va[kc][1].z) | ((unsigned)f2bf(va[kc][1].w) << 16);
      *(uint4*)(xrow + kc * 32) = u;
    }
#pragma unroll
    for (int kc = 0; kc < 4; ++kc) {
      uint2 s0 = split2(va[kc][0].x, va[kc][0].y);
      uint2 s1 = split2(va[kc][0].z, va[kc][0].w);
      uint2 s2 = split2(va[kc][1].x, va[kc][1].y);
      uint2 s3 = split2(va[kc][1].z, va[kc][1].w);
      uint4v hu, lu;
      hu[0] = s0.x; lu[0] = s0.y;
      hu[1] = s1.x; lu[1] = s1.y;
      hu[2] = s2.x; lu[2] = s2.y;
      hu[3] = s3.x; lu[3] = s3.y;
      bf16x8 ahi = __builtin_bit_cast(bf16x8, hu);
      bf16x8 alo = __builtin_bit_cast(bf16x8, lu);
      // SWAPPED operands: A = Wr fragments, B = x fragments -> C[expert][token]
#pragma unroll
      for (int mt = 0; mt < 2; ++mt) {
        acc[mt] = __builtin_amdgcn_mfma_f32_16x16x32_bf16(bfr[0][mt][kc], ahi, acc[mt], 0, 0, 0);
        acc[mt] = __builtin_amdgcn_mfma_f32_16x16x32_bf16(bfr[1][mt][kc], ahi, acc[mt], 0, 0, 0);
        acc[mt] = __builtin_amdgcn_mfma_f32_16x16x32_bf16(bfr[0][mt][kc], alo, acc[mt], 0, 0, 0);
      }
    }
  }

  // lane holds 8 biased logits for token tok0+l15: expert = mt*16 + quad*4 + r
  float4 brq0 = *(const float4*)(br + quad * 4);
  float4 brq1 = *(const float4*)(br + 16 + quad * 4);
  float le[2][4];
  le[0][0] = acc[0][0] + brq0.x; le[0][1] = acc[0][1] + brq0.y;
  le[0][2] = acc[0][2] + brq0.z; le[0][3] = acc[0][3] + brq0.w;
  le[1][0] = acc[1][0] + brq1.x; le[1][1] = acc[1][1] + brq1.y;
  le[1][2] = acc[1][2] + brq1.z; le[1][3] = acc[1][3] + brq1.w;

  const float NINF = -3.0e38f;
  // in-lane top-3 (increasing index order + strict '>' = lowest-index tiebreak)
  float v1 = NINF, v2 = NINF, v3 = NINF;
  int i1 = 0, i2 = 0;
#pragma unroll
  for (int mt = 0; mt < 2; ++mt)
#pragma unroll
    for (int r = 0; r < 4; ++r) {
      float v = le[mt][r];
      int idx = mt * 16 + quad * 4 + r;
      if (v > v1) { v3 = v2; v2 = v1; i2 = i1; v1 = v; i1 = idx; }
      else if (v > v2) { v3 = v2; v2 = v; i2 = idx; }
      else if (v > v3) { v3 = v; }
    }
  // 2-step cross-quad merge (lanes l15, 16+l15, 32+l15, 48+l15 share a token)
#pragma unroll
  for (int off = 16; off <= 32; off <<= 1) {
    float ov1 = __shfl_xor(v1, off); int oi1 = __shfl_xor(i1, off);
    float ov2 = __shfl_xor(v2, off); int oi2 = __shfl_xor(i2, off);
    float ov3 = __shfl_xor(v3, off);
    bool ob = (ov1 > v1) || (ov1 == v1 && oi1 < i1);
    float a1 = ob ? ov1 : v1;  int ai1 = ob ? oi1 : i1;
    float a2 = ob ? ov2 : v2;  int ai2 = ob ? oi2 : i2;
    float a3 = ob ? ov3 : v3;
    float b1v = ob ? v1 : ov1; int bi1 = ob ? i1 : oi1;
    float b2v = ob ? v2 : ov2;
    bool bb = (b1v > a2) || (b1v == a2 && bi1 < ai2);
    v1 = a1; i1 = ai1;
    if (bb) { v2 = b1v; i2 = bi1; v3 = (b2v > a2) ? b2v : a2; }
    else    { v2 = a2;  i2 = ai2; v3 = (b1v > a3) ? b1v : a3; }
  }
  // softmax denominator over all 32 experts
  float s = 0.f;
#pragma unroll
  for (int mt = 0; mt < 2; ++mt)
#pragma unroll
    for (int r = 0; r < 4; ++r) s += __expf(le[mt][r] - v1);
  s += __shfl_xor(s, 16);
  s += __shfl_xor(s, 32);

  if (quad == 0) {     // 16 lanes, consecutive tokens -> coalesced writes
    int n = tok0 + l15;
    int2 ti; ti.x = i1; ti.y = i2;
    float2 tv; tv.x = 1.0f / s; tv.y = __expf(v2 - v1) / s;
    ((int2*)top_idx)[n] = ti;
    ((float2*)top_val)[n] = tv;
    atomicAdd(&hc[i1], 1);
    atomicAdd(&hc[i2], 1);
    atomicAdd(&hf[i1], tv.x);
    atomicAdd(&hf[i2], tv.y);
    if (v2 - v3 < 2e-3f) {
      int si = atomicAdd(&scount, 1);
      if (si < 64) slist[si] = n;
    }
  }
  __syncthreads();

  // ---------- inline fp64 re-resolution of this block's near-tie tokens ----------
  int sc = scount;
  for (int ss = (t >> 5); ss < sc; ss += 8) {
    int lt = t & 31;
    int n = slist[ss];
    const float* xr = x + (size_t)n * DIM;
    double a = 0.0;
#pragma unroll 8
    for (int d = 0; d < DIM; ++d) a = fma((double)xr[d], (double)Wr[d * NE + lt], a);
    double lv = a + (double)br[lt];

    double dv1 = lv; int di1 = lt;
#pragma unroll
    for (int off = 16; off > 0; off >>= 1) {
      double ov = __shfl_xor(dv1, off, 32);
      int oi = __shfl_xor(di1, off, 32);
      if (ov > dv1 || (ov == dv1 && oi < di1)) { dv1 = ov; di1 = oi; }
    }
    double lv2 = (lt == di1) ? -1.0e300 : lv;
    double dv2 = lv2; int di2 = lt;
#pragma unroll
    for (int off = 16; off > 0; off >>= 1) {
      double ov = __shfl_xor(dv2, off, 32);
      int oi = __shfl_xor(di2, off, 32);
      if (ov > dv2 || (ov == dv2 && oi < di2)) { dv2 = ov; di2 = oi; }
    }
    float p = expf((float)(lv - dv1));
    float ssum = p;
#pragma unroll
    for (int off = 16; off > 0; off >>= 1) ssum += __shfl_xor(ssum, off, 32);
    if (lt == 0) {
      int o1 = top_idx[n * 2 + 0];
      int o2 = top_idx[n * 2 + 1];
      float w1v = top_val[n * 2 + 0];
      float w2v = top_val[n * 2 + 1];
      float nv1 = 1.0f / ssum;
      float nv2 = expf((float)(dv2 - dv1)) / ssum;
      atomicAdd(&hc[o1], -1); atomicAdd(&hc[o2], -1);
      atomicAdd(&hc[di1], 1);  atomicAdd(&hc[di2], 1);
      atomicAdd(&hf[o1], -w1v); atomicAdd(&hf[o2], -w2v);
      atomicAdd(&hf[di1], nv1);  atomicAdd(&hf[di2], nv2);
      top_idx[n * 2 + 0] = di1;
      top_idx[n * 2 + 1] = di2;
      top_val[n * 2 + 0] = nv1;
      top_val[n * 2 + 1] = nv2;
    }
  }
  __syncthreads();
  if (t < NE) {
    histbuf[b * NE + t] = hc[t];
    impbuf[b * NE + t] = hf[t];
  }
}

// ---------------- k_scatter2: deterministic scatter + offsets/counts/loss + inv map ----------------
// histbuf has 1024 router-block rows (64 tokens each); scatter block b covers
// router blocks 2b and 2b+1. perm[pos] = token; inv[token*2+slot] = pos.
__global__ __launch_bounds__(256) void k_scatter2(
    const int* __restrict__ top_idx, const float* __restrict__ top_val,
    const int* __restrict__ histbuf, const float* __restrict__ impbuf,
    int* __restrict__ perm, float* __restrict__ gatev, int* __restrict__ inv,
    int* __restrict__ offsets, int* __restrict__ counts, float* __restrict__ out_loss) {
  __shared__ int pf[8][32], pb[8][32];
  __shared__ int offs[NE], pref[NE], h2[NE];
  int b = blockIdx.x, t = threadIdx.x;
  if (t < NE) h2[t] = 0;
  int g = t >> 5, e = t & 31;
  int sf = 0, sb = 0;
  for (int j = 0; j < 128; ++j) {
    int bb = g * 128 + j;
    int v = histbuf[bb * NE + e];
    sf += v;
    sb += (bb < 2 * b) ? v : 0;
  }
  pf[g][e] = sf;
  pb[g][e] = sb;
  __syncthreads();
  if (t < 32) {
    int T = 0, P = 0;
#pragma unroll
    for (int g2 = 0; g2 < 8; ++g2) { T += pf[g2][t]; P += pb[g2][t]; }
    int pc = (T + 63) & ~63;
    int scn = pc;
#pragma unroll
    for (int off = 1; off < 32; off <<= 1) {
      int ov = __shfl_up(scn, off, 32);
      if (t >= off) scn += ov;
    }
    offs[t] = scn - pc;
    pref[t] = P;
    if (b == 0) {
      offsets[t] = scn - pc;
      counts[t] = T;
      if (t == 31) offsets[NE] = scn;
    }
  }
  __syncthreads();
  if (t < 128) {
    int n = b * 128 + t;
    int2 ti = ((const int2*)top_idx)[n];
    float2 tv = ((const float2*)top_val)[n];
    int r0 = atomicAdd(&h2[ti.x], 1);
    int r1 = atomicAdd(&h2[ti.y], 1);
    int p0 = offs[ti.x] + pref[ti.x] + r0;
    int p1 = offs[ti.y] + pref[ti.y] + r1;
    perm[p0] = n;
    gatev[p0] = tv.x;
    perm[p1] = n;
    gatev[p1] = tv.y;
    int2 iv; iv.x = p0; iv.y = p1;
    ((int2*)inv)[n] = iv;
  }
  if (b == 0) {
    __shared__ float pfi[8][32];
    float s2 = 0.f;
    for (int j = 0; j < 128; ++j) s2 += impbuf[(g * 128 + j) * NE + e];
    pfi[g][e] = s2;
    __syncthreads();
    if (t < 32) {
      float imp = 0.f;
#pragma unroll
      for (int g2 = 0; g2 < 8; ++g2) imp += pfi[g2][t];
      float ssum = imp;
#pragma unroll
      for (int off = 16; off > 0; off >>= 1) ssum += __shfl_xor(ssum, off, 32);
      float mean = ssum / 32.0f;
      float dlt = imp - mean;
      float v = dlt * dlt;
#pragma unroll
      for (int off = 16; off > 0; off >>= 1) v += __shfl_xor(v, off, 32);
      if (t == 0) *out_loss = (v / 31.0f) / (mean * mean + 1e-9f);
    }
  }
}

// ---------------- fused expert GEMM: 64 tokens x 1 expert per block ----------------
// YB=1: gather via global_load_lds (direct-to-LDS, source pre-swizzled so linear
//       lane-order writes reproduce the LDSA XOR layout: lane l carries row l^(cc*2)).
// YB=0 (fallback): fp32 gather, atomic out.
// __launch_bounds__(256,3): no spill (VGPR 84 measured). Do NOT add live regs here:
// (256,4), held-gather, and cooperative variants all regressed (rounds 3/4/6/8).
template <int YB>
__global__ __launch_bounds__(256, 3) void k_expert(
    const float* __restrict__ x, const unsigned short* __restrict__ xb,
    const unsigned short* __restrict__ w1t, const unsigned short* __restrict__ w2t,
    const float* __restrict__ b1, const float* __restrict__ b2,
    const int* __restrict__ offsets, const int* __restrict__ counts,
    const int* __restrict__ perm, const float* __restrict__ gatev,
    unsigned short* __restrict__ ybuf, float* __restrict__ out) {
  __shared__ __align__(16) unsigned char smem[32768];   // xa: c 0..15; ha: c 0..31 (aliased)

  // XCD-affinity swizzle (2080 = 8*260, bijective)
  int bid = (int)(blockIdx.x & 7) * 260 + (int)(blockIdx.x >> 3);
  int slot0 = bid * 64;
  if (slot0 >= offsets[NE]) return;
  int e = 0;
#pragma unroll
  for (int i = 1; i < NE; ++i)
    if (slot0 >= offsets[i]) e = i;
  int cnt = counts[e];
  int local0 = slot0 - offsets[e];
  int nvalid = min(64, cnt - local0);

  int t = threadIdx.x;
  int w = t >> 6;
  int l = t & 63;
  int quad = l >> 4;
  int l15 = l & 15;

  int pvl = 0;
  float gvl = 0.f;
  if (YB) {
    // clamped perm load (nvalid >= 1 always); garbage rows are masked at store,
    // and never cross rows inside MFMA (each output row = dot of its own A row).
    int lc = (l < nvalid) ? l : (nvalid - 1);
    pvl = perm[slot0 + lc];
    if (l < nvalid) gvl = gatev[slot0 + l];
    // Direct-to-LDS gather: for chunk c, linear slot l must hold row l^(cc*2)
    // (LDSA's XOR only touches byte-bits 5-6 = lane-bits 1-2). shfl_xor delivers
    // that row's perm value; all 64 lanes active.
#pragma unroll
    for (int cc = 0; cc < 4; ++cc) {
      int c = w * 4 + cc;
      int pv = (cc == 0) ? pvl : __shfl_xor(pvl, cc * 2);
      const unsigned short* gsrc = xb + (size_t)pv * DIM + c * 8;
      las_uint* ldsb = (las_uint*)(smem + c * 1024);
      __builtin_amdgcn_global_load_lds((gas_uint*)gsrc, ldsb, 16, 0, 0);
    }
  } else {
    unsigned pk[16];
    if (l < nvalid) {
      pvl = perm[slot0 + l];
      gvl = gatev[slot0 + l];
      const float* src = x + (size_t)pvl * DIM + w * 32;
#pragma unroll
      for (int q = 0; q < 8; ++q) {
        float4 vv = ((const float4*)src)[q];
        pk[q * 2 + 0] = (unsigned)f2bf(vv.x) | ((unsigned)f2bf(vv.y) << 16);
        pk[q * 2 + 1] = (unsigned)f2bf(vv.z) | ((unsigned)f2bf(vv.w) << 16);
      }
    } else {
#pragma unroll
      for (int q = 0; q < 16; ++q) pk[q] = 0u;
    }
#pragma unroll
    for (int cc = 0; cc < 4; ++cc) {
      uint4 u;
      u.x = pk[cc * 4 + 0]; u.y = pk[cc * 4 + 1]; u.z = pk[cc * 4 + 2]; u.w = pk[cc * 4 + 3];
      *(uint4*)(smem + LDSA(w * 4 + cc, l, 0)) = u;
    }
  }

  const unsigned short* w1e = w1t + (size_t)e * DIM * HID;
  bf16x8 w1f[4][4];
#pragma unroll
  for (int kc = 0; kc < 4; ++kc)
#pragma unroll
    for (int jt = 0; jt < 4; ++jt)
      w1f[kc][jt] = *(const bf16x8*)(w1e + kc * 8192 + (w * 64 + jt * 16 + l15) * 32 + quad * 8);

  __syncthreads();   // (1) xa staged (vmcnt(0) drain covers global_load_lds)

  f32x4 acc[4][4];
#pragma unroll
  for (int a = 0; a < 4; ++a)
#pragma unroll
    for (int bb = 0; bb < 4; ++bb) {
      f32x4 z = {0.f, 0.f, 0.f, 0.f};
      acc[a][bb] = z;
    }
#pragma unroll
  for (int kc = 0; kc < 4; ++kc) {
    bf16x8 af[4];
#pragma unroll
    for (int rt = 0; rt < 4; ++rt)
      af[rt] = *(const bf16x8*)(smem + LDSA(kc * 4 + quad, rt * 16 + l15, 0));
#pragma unroll
    for (int rt = 0; rt < 4; ++rt)
#pragma unroll
      for (int jt = 0; jt < 4; ++jt)
        acc[rt][jt] = __builtin_amdgcn_mfma_f32_16x16x32_bf16(af[rt], w1f[kc][jt], acc[rt][jt], 0, 0, 0);
  }

  const unsigned short* w2e = w2t + (size_t)e * HID * DIM;
  bf16x8 w2f[8][2];
#pragma unroll
  for (int hc = 0; hc < 8; ++hc)
#pragma unroll
    for (int jt = 0; jt < 2; ++jt)
      w2f[hc][jt] = *(const bf16x8*)(w2e + hc * 4096 + (w * 32 + jt * 16 + l15) * 32 + quad * 8);

  __syncthreads();   // (2) all xa reads done; ha may overwrite

  // GEMM1 epilogue: lane's 4 jt-values are h = w*64 + 4*l15 + {0..3} -> one b64 write
  {
    float4 b1v = *(const float4*)(b1 + e * HID + w * 64 + 4 * l15);
    int c = w * 8 + (l15 >> 1);
    int byte = (l15 & 1) * 8;
#pragma unroll
    for (int rt = 0; rt < 4; ++rt) {
#pragma unroll
      for (int r = 0; r < 4; ++r) {
        int tokrow = rt * 16 + quad * 4 + r;
        float v0 = acc[rt][0][r] + b1v.x; v0 = v0 > 0.f ? v0 : 0.f;
        float v1 = acc[rt][1][r] + b1v.y; v1 = v1 > 0.f ? v1 : 0.f;
        float v2 = acc[rt][2][r] + b1v.z; v2 = v2 > 0.f ? v2 : 0.f;
        float v3 = acc[rt][3][r] + b1v.w; v3 = v3 > 0.f ? v3 : 0.f;
        uint2 u;
        u.x = (unsigned)f2bf(v0) | ((unsigned)f2bf(v1) << 16);
        u.y = (unsigned)f2bf(v2) | ((unsigned)f2bf(v3) << 16);
        *(uint2*)(smem + LDSA(c, tokrow, byte)) = u;
      }
    }
  }
  __syncthreads();   // (3) ha ready

  f32x4 accc[4][2];
#pragma unroll
  for (int a = 0; a < 4; ++a)
#pragma unroll
    for (int bb = 0; bb < 2; ++bb) {
      f32x4 z = {0.f, 0.f, 0.f, 0.f};
      accc[a][bb] = z;
    }
#pragma unroll
  for (int hc = 0; hc < 8; ++hc) {
    bf16x8 ah[4];
#pragma unroll
    for (int rt = 0; rt < 4; ++rt)
      ah[rt] = *(const bf16x8*)(smem + LDSA(hc * 4 + quad, rt * 16 + l15, 0));
#pragma unroll
    for (int rt = 0; rt < 4; ++rt)
#pragma unroll
      for (int jt = 0; jt < 2; ++jt)
        accc[rt][jt] = __builtin_amdgcn_mfma_f32_16x16x32_bf16(ah[rt], w2f[hc][jt], accc[rt][jt], 0, 0, 0);
  }

  // GEMM2 epilogue: lane's 2 jt-values are d = w*32 + 2*l15 + {0,1} -> one 4B store.
  // Slot-addressed ybuf: block writes rows slot0..slot0+63 (contiguous stream).
  int dbase = w * 32;
  float2 b2v = *(const float2*)(b2 + e * DIM + dbase + 2 * l15);
#pragma unroll
  for (int rt = 0; rt < 4; ++rt) {
#pragma unroll
    for (int r = 0; r < 4; ++r) {
      int tokrow = rt * 16 + quad * 4 + r;
      int pv = __shfl(pvl, tokrow);     // all lanes participate
      float g = __shfl(gvl, tokrow);
      if (tokrow < nvalid) {
        float y0 = g * (accc[rt][0][r] + b2v.x);
        float y1 = g * (accc[rt][1][r] + b2v.y);
        if (YB) {
          unsigned pack = (unsigned)f2bf(y0) | ((unsigned)f2bf(y1) << 16);
          *(unsigned*)(ybuf + (size_t)(slot0 + tokrow) * DIM + dbase + 2 * l15) = pack;
        } else {
          float* orow = out + (size_t)pv * DIM + dbase + 2 * l15;
          atomicAdd(&orow[0], y0);
          atomicAdd(&orow[1], y1);
        }
      }
    }
  }
}

// ---------------- combine: out[n] = ybuf[inv[2n]] + ybuf[inv[2n+1]] ----------------
// 32 tokens/block (2 unrolled iterations) to halve block count / launch+tail overhead.
__global__ __launch_bounds__(256) void k_combine(const unsigned short* __restrict__ ybuf,
                                                 const int* __restrict__ inv,
                                                 float* __restrict__ out) {
  int t = threadIdx.x;
  int lane = t & 15;
#pragma unroll
  for (int j = 0; j < 2; ++j) {
    int n = blockIdx.x * 32 + j * 16 + (t >> 4);
    int2 iv = ((const int2*)inv)[n];
    uint4 a = *((const uint4*)(ybuf + (size_t)iv.x * DIM) + lane);
    uint4 b = *((const uint4*)(ybuf + (size_t)iv.y * DIM) + lane);
    unsigned av[4] = {a.x, a.y, a.z, a.w}, bv[4] = {b.x, b.y, b.z, b.w};
    float r[8];
#pragma unroll
    for (int q = 0; q < 4; ++q) {
      r[q * 2 + 0] = bf2f(av[q] & 0xffffu) + bf2f(bv[q] & 0xffffu);
      r[q * 2 + 1] = bf2f(av[q] >> 16) + bf2f(bv[q] >> 16);
    }
    float* orow = out + (size_t)n * DIM + lane * 8;
    float4 w0 = {r[0], r[1], r[2], r[3]}, w1 = {r[4], r[5], r[6], r[7]};
    ((float4*)orow)[0] = w0;
    ((float4*)orow)[1] = w1;
  }
}

extern "C" void kernel_launch(void* const* d_in, const int* in_sizes, int n_in,
                              void* d_out, int out_size, void* d_ws, size_t ws_size,
                              hipStream_t stream) {
  const float* x  = (const float*)d_in[0];
  const float* W1 = (const float*)d_in[1];
  const float* b1 = (const float*)d_in[2];
  const float* W2 = (const float*)d_in[3];
  const float* b2 = (const float*)d_in[4];
  const float* Wr = (const float*)d_in[5];
  const float* br = (const float*)d_in[6];
  float* out = (float*)d_out;

  char* ws = (char*)d_ws;
  int*   counts   = (int*)(ws + 0);         // 32 i
  int*   offsets  = (int*)(ws + 128);       // 33 i
  int*   top_idx  = (int*)(ws + 1024);      // 131072 i -> 525312
  float* top_val  = (float*)(ws + 525312);  // 131072 f -> 1049600
  int*   perm     = (int*)(ws + 1049600);   // 133120 i -> 1582080
  float* gatev    = (float*)(ws + 1582080); // 133120 f -> 2114560
  int*   inv      = (int*)(ws + 2114560);   // 131072 i -> 2638848
  int*   histbuf  = (int*)(ws + 2638848);   // 1024*32 i -> 2769920
  float* impbuf   = (float*)(ws + 2769920); // 1024*32 f -> 2900992
  unsigned short* w1t = (unsigned short*)(ws + 2900992);  // 2 MB -> 4998144
  unsigned short* w2t = (unsigned short*)(ws + 4998144);  // 2 MB -> 7095296
  unsigned short* ybuf = (unsigned short*)(ws + 7095296); // 34078720 -> 41174016
  const size_t NEEDED = 41174016;
  bool use_ybuf = ws_size >= NEEDED;

  // bf16 copy of x in the head of `out` (16.8 MB): written by k_front's router
  // blocks, consumed by k_expert<1>, fully overwritten by k_combine afterwards.
  unsigned short* xb = (unsigned short*)out;

  if (use_ybuf) {
    hipLaunchKernelGGL(k_front, dim3(1536), dim3(256), 0, stream, x, W1, W2, Wr, br,
                       top_idx, top_val, xb, w1t, w2t, histbuf, impbuf);
    hipLaunchKernelGGL(k_scatter2, dim3(512), dim3(256), 0, stream, top_idx, top_val,
                       histbuf, impbuf, perm, gatev, inv, offsets, counts,
                       out + (size_t)N_TOK * DIM);
    hipLaunchKernelGGL((k_expert<1>), dim3(2080), dim3(256), 0, stream, x, xb, w1t, w2t,
                       b1, b2, offsets, counts, perm, gatev, ybuf, out);
    hipLaunchKernelGGL(k_combine, dim3(2048), dim3(256), 0, stream, ybuf, inv, out);
  } else {
    hipLaunchKernelGGL(k_front, dim3(1536), dim3(256), 0, stream, x, W1, W2, Wr, br,
                       top_idx, top_val, xb, w1t, w2t, histbuf, impbuf);
    hipLaunchKernelGGL(k_scatter2, dim3(512), dim3(256), 0, stream, top_idx, top_val,
                       histbuf, impbuf, perm, gatev, inv, offsets, counts,
                       out + (size_t)N_TOK * DIM);
    hipLaunchKernelGGL(k_zero_out, dim3(4096), dim3(256), 0, stream, out);
    hipLaunchKernelGGL((k_expert<0>), dim3(2080), dim3(256), 0, stream, x,
                       (const unsigned short*)0, w1t, w2t, b1, b2, offsets, counts,
                       perm, gatev, (unsigned short*)0, out);
  }
}

// Round 12
// 174.954 us; speedup vs baseline: 1.0196x; 1.0196x over previous
//
#include <hip/hip_runtime.h>
#include <hip/hip_bf16.h>
#include <cstdint>
#include <cstddef>

#define N_TOK 65536
#define DIM 128
#define HID 256
#define NE 32
#define TOPK 2

typedef __bf16 bf16x8 __attribute__((ext_vector_type(8)));
typedef float f32x4 __attribute__((ext_vector_type(4)));
typedef unsigned uint4v __attribute__((ext_vector_type(4)));

// LDS address with XOR swizzle: inject c's low 2 bits into bank bits 5-6.
#define LDSA(c, row, byte) ((((c) * 1024 + (row) * 16 + (byte))) ^ ((((c) & 3) << 5)))

__device__ __forceinline__ unsigned short f2bf(float f) {
  unsigned u = __builtin_bit_cast(unsigned, f);
  u += 0x7fffu + ((u >> 16) & 1u);   // round-to-nearest-even
  return (unsigned short)(u >> 16);
}
__device__ __forceinline__ float bf2f(unsigned s) {
  return __builtin_bit_cast(float, s << 16);
}
// truncation split: f = hi + lo + O(2^-14 |f|); packs two values' shorts into one uint.
__device__ __forceinline__ uint2 split2(float f0, float f1) {
  unsigned u0 = __builtin_bit_cast(unsigned, f0);
  unsigned u1 = __builtin_bit_cast(unsigned, f1);
  unsigned hi = (u0 >> 16) | (u1 & 0xffff0000u);
  float r0 = f0 - __builtin_bit_cast(float, u0 & 0xffff0000u);
  float r1 = f1 - __builtin_bit_cast(float, u1 & 0xffff0000u);
  unsigned lo = (__builtin_bit_cast(unsigned, r0) >> 16) |
                (__builtin_bit_cast(unsigned, r1) & 0xffff0000u);
  uint2 ret; ret.x = hi; ret.y = lo;
  return ret;
}

// ---------------- fallback-only: zero out ----------------
__global__ void k_zero_out(float* __restrict__ out) {
  int t = blockIdx.x * 256 + threadIdx.x;
  float4 z = make_float4(0.f, 0.f, 0.f, 0.f);
  float4* o4 = (float4*)out;
  o4[t] = z;
  o4[t + 1048576] = z;
}

// ---------------- k_front: router (+inline fp64 fix, hist, xb) + weight transpose ----------------
// blocks 0..1023:    router, 64 tokens each. blocks 1024..1535: W1/W2 bf16 transpose.
// Router uses SWAPPED mfma operands (Wr as A, x as B) so C is [expert][token]:
// each lane holds 8 expert-logits for ONE token -> top-3 is 8 serial compares +
// 2 shfl-merge steps instead of 12 butterfly passes. Logit values bit-identical.
__global__ __launch_bounds__(256, 3) void k_front(
    const float* __restrict__ x, const float* __restrict__ W1,
    const float* __restrict__ W2, const float* __restrict__ Wr,
    const float* __restrict__ br,
    int* __restrict__ top_idx, float* __restrict__ top_val,
    unsigned short* __restrict__ xb,
    unsigned short* __restrict__ w1t, unsigned short* __restrict__ w2t,
    int* __restrict__ histbuf, float* __restrict__ impbuf) {
  int b = blockIdx.x;
  int t = threadIdx.x;

  if (b >= 1024) {
    // ---------- weight transpose ----------
    int bb = b - 1024;
    const float* in;
    unsigned short* outp;
    int K, r0, c0;
    bool isW1;
    if (bb < 256) {
      int e = bb >> 3, tt = bb & 7;
      in = W1 + (size_t)e * DIM * HID;   // [d][h] 128x256
      outp = w1t + (size_t)e * DIM * HID;
      K = HID;
      r0 = (tt >> 2) * 64; c0 = (tt & 3) * 64;
      isW1 = true;
    } else {
      bb -= 256;
      int e = bb >> 3, tt = bb & 7;
      in = W2 + (size_t)e * HID * DIM;   // [h][d] 256x128
      outp = w2t + (size_t)e * HID * DIM;
      K = DIM;
      r0 = (tt >> 1) * 64; c0 = (tt & 1) * 64;
      isW1 = false;
    }
    __shared__ float tile[64][65];
    int r = t >> 2, cs = (t & 3) * 16;
    const float* src = in + (size_t)(r0 + r) * K + c0 + cs;
#pragma unroll
    for (int j = 0; j < 4; ++j) {
      float4 v = *(const float4*)(src + j * 4);
      tile[r][cs + j * 4 + 0] = v.x;
      tile[r][cs + j * 4 + 1] = v.y;
      tile[r][cs + j * 4 + 2] = v.z;
      tile[r][cs + j * 4 + 3] = v.w;
    }
    __syncthreads();
#pragma unroll
    for (int p = 0; p < 2; ++p) {
      int orow = p * 32 + (t >> 3);
      int oc8 = (t & 7) * 8;
      int rr = r0 + oc8;
      unsigned pk[4];
#pragma unroll
      for (int q = 0; q < 4; ++q) {
        unsigned lo = f2bf(tile[oc8 + 2 * q][orow]);
        unsigned hi = f2bf(tile[oc8 + 2 * q + 1][orow]);
        pk[q] = lo | (hi << 16);
      }
      uint4 u;
      u.x = pk[0]; u.y = pk[1]; u.z = pk[2]; u.w = pk[3];
      int h = c0 + orow;
      int hp = isW1 ? ((h & ~63) | ((h & 3) << 4) | ((h & 63) >> 2))
                    : ((h & ~31) | ((h & 1) << 4) | ((h & 31) >> 1));
      size_t addr = (size_t)(rr >> 5) * (K * 32) + (size_t)hp * 32 + (rr & 31);
      *(uint4*)(outp + addr) = u;
    }
    return;
  }

  // ---------- router: 64 tokens/block ----------
  __shared__ int hc[NE];
  __shared__ float hf[NE];
  __shared__ int slist[64];
  __shared__ int scount;
  if (t < NE) { hc[t] = 0; hf[t] = 0.f; }
  if (t == 0) scount = 0;
  __syncthreads();

  int w = t >> 6, l = t & 63, quad = l >> 4, l15 = l & 15;
  int tok0 = b * 64 + w * 16;

  // Build Wr fragments (hi/lo split) directly from Wr (L1/L2-hot 16 KB table).
  bf16x8 bfr[2][2][4];
#pragma unroll
  for (int nt = 0; nt < 2; ++nt)
#pragma unroll
    for (int kc = 0; kc < 4; ++kc) {
      unsigned hiw[4], low[4];
#pragma unroll
      for (int jp = 0; jp < 4; ++jp) {
        int k0 = kc * 32 + quad * 8 + jp * 2;
        int e = nt * 16 + l15;
        float w0 = Wr[k0 * NE + e];
        float w1v = Wr[(k0 + 1) * NE + e];
        uint2 s = split2(w0, w1v);
        hiw[jp] = s.x; low[jp] = s.y;
      }
      uint4v h4, l4;
      h4[0] = hiw[0]; h4[1] = hiw[1]; h4[2] = hiw[2]; h4[3] = hiw[3];
      l4[0] = low[0]; l4[1] = low[1]; l4[2] = low[2]; l4[3] = low[3];
      bfr[0][nt][kc] = __builtin_bit_cast(bf16x8, h4);
      bfr[1][nt][kc] = __builtin_bit_cast(bf16x8, l4);
    }

  f32x4 acc[2];
#pragma unroll
  for (int a = 0; a < 2; ++a) {
    f32x4 z = {0.f, 0.f, 0.f, 0.f};
    acc[a] = z;
  }

  {
    const float* xp = x + (size_t)(tok0 + l15) * DIM + quad * 8;
    float4 va[4][2];
#pragma unroll
    for (int kc = 0; kc < 4; ++kc) {
      const float4* p = (const float4*)(xp + kc * 32);
      va[kc][0] = p[0];
      va[kc][1] = p[1];
    }
    // bf16 row-major copy of x for k_expert's gather
    unsigned short* xrow = xb + (size_t)(tok0 + l15) * DIM + quad * 8;
#pragma unroll
    for (int kc = 0; kc < 4; ++kc) {
      uint4 u;
      u.x = (unsigned)f2bf(va[kc][0].x) | ((unsigned)f2bf(va[kc][0].y) << 16);
      u.y = (unsigned)f2bf(va[kc][0].z) | ((unsigned)f2bf(va[kc][0].w) << 16);
      u.z = (unsigned)f2bf(va[kc][1].x) | ((unsigned)f2bf(va[kc][1].y) << 16);
      u.w = (unsigned)f2bf(va[kc][1].z) | ((unsigned)f2bf(va[kc][1].w) << 16);
      *(uint4*)(xrow + kc * 32) = u;
    }
#pragma unroll
    for (int kc = 0; kc < 4; ++kc) {
      uint2 s0 = split2(va[kc][0].x, va[kc][0].y);
      uint2 s1 = split2(va[kc][0].z, va[kc][0].w);
      uint2 s2 = split2(va[kc][1].x, va[kc][1].y);
      uint2 s3 = split2(va[kc][1].z, va[kc][1].w);
      uint4v hu, lu;
      hu[0] = s0.x; lu[0] = s0.y;
      hu[1] = s1.x; lu[1] = s1.y;
      hu[2] = s2.x; lu[2] = s2.y;
      hu[3] = s3.x; lu[3] = s3.y;
      bf16x8 ahi = __builtin_bit_cast(bf16x8, hu);
      bf16x8 alo = __builtin_bit_cast(bf16x8, lu);
      // SWAPPED operands: A = Wr fragments, B = x fragments -> C[expert][token]
#pragma unroll
      for (int mt = 0; mt < 2; ++mt) {
        acc[mt] = __builtin_amdgcn_mfma_f32_16x16x32_bf16(bfr[0][mt][kc], ahi, acc[mt], 0, 0, 0);
        acc[mt] = __builtin_amdgcn_mfma_f32_16x16x32_bf16(bfr[1][mt][kc], ahi, acc[mt], 0, 0, 0);
        acc[mt] = __builtin_amdgcn_mfma_f32_16x16x32_bf16(bfr[0][mt][kc], alo, acc[mt], 0, 0, 0);
      }
    }
  }

  // lane holds 8 biased logits for token tok0+l15: expert = mt*16 + quad*4 + r
  float4 brq0 = *(const float4*)(br + quad * 4);
  float4 brq1 = *(const float4*)(br + 16 + quad * 4);
  float le[2][4];
  le[0][0] = acc[0][0] + brq0.x; le[0][1] = acc[0][1] + brq0.y;
  le[0][2] = acc[0][2] + brq0.z; le[0][3] = acc[0][3] + brq0.w;
  le[1][0] = acc[1][0] + brq1.x; le[1][1] = acc[1][1] + brq1.y;
  le[1][2] = acc[1][2] + brq1.z; le[1][3] = acc[1][3] + brq1.w;

  const float NINF = -3.0e38f;
  // in-lane top-3 (increasing index order + strict '>' = lowest-index tiebreak)
  float v1 = NINF, v2 = NINF, v3 = NINF;
  int i1 = 0, i2 = 0;
#pragma unroll
  for (int mt = 0; mt < 2; ++mt)
#pragma unroll
    for (int r = 0; r < 4; ++r) {
      float v = le[mt][r];
      int idx = mt * 16 + quad * 4 + r;
      if (v > v1) { v3 = v2; v2 = v1; i2 = i1; v1 = v; i1 = idx; }
      else if (v > v2) { v3 = v2; v2 = v; i2 = idx; }
      else if (v > v3) { v3 = v; }
    }
  // 2-step cross-quad merge (lanes l15, 16+l15, 32+l15, 48+l15 share a token)
#pragma unroll
  for (int off = 16; off <= 32; off <<= 1) {
    float ov1 = __shfl_xor(v1, off); int oi1 = __shfl_xor(i1, off);
    float ov2 = __shfl_xor(v2, off); int oi2 = __shfl_xor(i2, off);
    float ov3 = __shfl_xor(v3, off);
    bool ob = (ov1 > v1) || (ov1 == v1 && oi1 < i1);
    float a1 = ob ? ov1 : v1;  int ai1 = ob ? oi1 : i1;
    float a2 = ob ? ov2 : v2;  int ai2 = ob ? oi2 : i2;
    float a3 = ob ? ov3 : v3;
    float b1v = ob ? v1 : ov1; int bi1 = ob ? i1 : oi1;
    float b2v = ob ? v2 : ov2;
    bool bb = (b1v > a2) || (b1v == a2 && bi1 < ai2);
    v1 = a1; i1 = ai1;
    if (bb) { v2 = b1v; i2 = bi1; v3 = (b2v > a2) ? b2v : a2; }
    else    { v2 = a2;  i2 = ai2; v3 = (b1v > a3) ? b1v : a3; }
  }
  // softmax denominator over all 32 experts
  float s = 0.f;
#pragma unroll
  for (int mt = 0; mt < 2; ++mt)
#pragma unroll
    for (int r = 0; r < 4; ++r) s += __expf(le[mt][r] - v1);
  s += __shfl_xor(s, 16);
  s += __shfl_xor(s, 32);

  if (quad == 0) {     // 16 lanes, consecutive tokens -> coalesced writes
    int n = tok0 + l15;
    int2 ti; ti.x = i1; ti.y = i2;
    float2 tv; tv.x = 1.0f / s; tv.y = __expf(v2 - v1) / s;
    ((int2*)top_idx)[n] = ti;
    ((float2*)top_val)[n] = tv;
    atomicAdd(&hc[i1], 1);
    atomicAdd(&hc[i2], 1);
    atomicAdd(&hf[i1], tv.x);
    atomicAdd(&hf[i2], tv.y);
    if (v2 - v3 < 2e-3f) {
      int si = atomicAdd(&scount, 1);
      if (si < 64) slist[si] = n;
    }
  }
  __syncthreads();

  // ---------- inline fp64 re-resolution of this block's near-tie tokens ----------
  int sc = scount;
  for (int ss = (t >> 5); ss < sc; ss += 8) {
    int lt = t & 31;
    int n = slist[ss];
    const float* xr = x + (size_t)n * DIM;
    double a = 0.0;
#pragma unroll 8
    for (int d = 0; d < DIM; ++d) a = fma((double)xr[d], (double)Wr[d * NE + lt], a);
    double lv = a + (double)br[lt];

    double dv1 = lv; int di1 = lt;
#pragma unroll
    for (int off = 16; off > 0; off >>= 1) {
      double ov = __shfl_xor(dv1, off, 32);
      int oi = __shfl_xor(di1, off, 32);
      if (ov > dv1 || (ov == dv1 && oi < di1)) { dv1 = ov; di1 = oi; }
    }
    double lv2 = (lt == di1) ? -1.0e300 : lv;
    double dv2 = lv2; int di2 = lt;
#pragma unroll
    for (int off = 16; off > 0; off >>= 1) {
      double ov = __shfl_xor(dv2, off, 32);
      int oi = __shfl_xor(di2, off, 32);
      if (ov > dv2 || (ov == dv2 && oi < di2)) { dv2 = ov; di2 = oi; }
    }
    float p = expf((float)(lv - dv1));
    float ssum = p;
#pragma unroll
    for (int off = 16; off > 0; off >>= 1) ssum += __shfl_xor(ssum, off, 32);
    if (lt == 0) {
      int o1 = top_idx[n * 2 + 0];
      int o2 = top_idx[n * 2 + 1];
      float w1v = top_val[n * 2 + 0];
      float w2v = top_val[n * 2 + 1];
      float nv1 = 1.0f / ssum;
      float nv2 = expf((float)(dv2 - dv1)) / ssum;
      atomicAdd(&hc[o1], -1); atomicAdd(&hc[o2], -1);
      atomicAdd(&hc[di1], 1);  atomicAdd(&hc[di2], 1);
      atomicAdd(&hf[o1], -w1v); atomicAdd(&hf[o2], -w2v);
      atomicAdd(&hf[di1], nv1);  atomicAdd(&hf[di2], nv2);
      top_idx[n * 2 + 0] = di1;
      top_idx[n * 2 + 1] = di2;
      top_val[n * 2 + 0] = nv1;
      top_val[n * 2 + 1] = nv2;
    }
  }
  __syncthreads();
  if (t < NE) {
    histbuf[b * NE + t] = hc[t];
    impbuf[b * NE + t] = hf[t];
  }
}

// ---------------- k_scatter2: deterministic scatter + offsets/counts/loss + inv map ----------------
// histbuf has 1024 router-block rows (64 tokens each); scatter block b covers
// router blocks 2b and 2b+1. perm[pos] = token; inv[token*2+slot] = pos.
__global__ __launch_bounds__(256) void k_scatter2(
    const int* __restrict__ top_idx, const float* __restrict__ top_val,
    const int* __restrict__ histbuf, const float* __restrict__ impbuf,
    int* __restrict__ perm, float* __restrict__ gatev, int* __restrict__ inv,
    int* __restrict__ offsets, int* __restrict__ counts, float* __restrict__ out_loss) {
  __shared__ int pf[8][32], pb[8][32];
  __shared__ int offs[NE], pref[NE], h2[NE];
  int b = blockIdx.x, t = threadIdx.x;
  if (t < NE) h2[t] = 0;
  int g = t >> 5, e = t & 31;
  int sf = 0, sb = 0;
  for (int j = 0; j < 128; ++j) {
    int bb = g * 128 + j;
    int v = histbuf[bb * NE + e];
    sf += v;
    sb += (bb < 2 * b) ? v : 0;
  }
  pf[g][e] = sf;
  pb[g][e] = sb;
  __syncthreads();
  if (t < 32) {
    int T = 0, P = 0;
#pragma unroll
    for (int g2 = 0; g2 < 8; ++g2) { T += pf[g2][t]; P += pb[g2][t]; }
    int pc = (T + 63) & ~63;
    int scn = pc;
#pragma unroll
    for (int off = 1; off < 32; off <<= 1) {
      int ov = __shfl_up(scn, off, 32);
      if (t >= off) scn += ov;
    }
    offs[t] = scn - pc;
    pref[t] = P;
    if (b == 0) {
      offsets[t] = scn - pc;
      counts[t] = T;
      if (t == 31) offsets[NE] = scn;
    }
  }
  __syncthreads();
  if (t < 128) {
    int n = b * 128 + t;
    int2 ti = ((const int2*)top_idx)[n];
    float2 tv = ((const float2*)top_val)[n];
    int r0 = atomicAdd(&h2[ti.x], 1);
    int r1 = atomicAdd(&h2[ti.y], 1);
    int p0 = offs[ti.x] + pref[ti.x] + r0;
    int p1 = offs[ti.y] + pref[ti.y] + r1;
    perm[p0] = n;
    gatev[p0] = tv.x;
    perm[p1] = n;
    gatev[p1] = tv.y;
    int2 iv; iv.x = p0; iv.y = p1;
    ((int2*)inv)[n] = iv;
  }
  if (b == 0) {
    __shared__ float pfi[8][32];
    float s2 = 0.f;
    for (int j = 0; j < 128; ++j) s2 += impbuf[(g * 128 + j) * NE + e];
    pfi[g][e] = s2;
    __syncthreads();
    if (t < 32) {
      float imp = 0.f;
#pragma unroll
      for (int g2 = 0; g2 < 8; ++g2) imp += pfi[g2][t];
      float ssum = imp;
#pragma unroll
      for (int off = 16; off > 0; off >>= 1) ssum += __shfl_xor(ssum, off, 32);
      float mean = ssum / 32.0f;
      float dlt = imp - mean;
      float v = dlt * dlt;
#pragma unroll
      for (int off = 16; off > 0; off >>= 1) v += __shfl_xor(v, off, 32);
      if (t == 0) *out_loss = (v / 31.0f) / (mean * mean + 1e-9f);
    }
  }
}

// ---------------- fused expert GEMM: 64 tokens x 1 expert per block (round-10 exact) ----------------
// YB=1: reg-staged bf16 gather from xb (4 independent dwordx4 loads -> max ILP),
// slot-addressed (contiguous) ybuf output. YB=0 (fallback): fp32 gather, atomic out.
// __launch_bounds__(256,3): no spill (VGPR 84 measured). Do NOT add live regs here:
// (256,4), held-gather, cooperative, and lds-direct-gather variants all regressed
// (rounds 3/4/6/8/11).
template <int YB>
__global__ __launch_bounds__(256, 3) void k_expert(
    const float* __restrict__ x, const unsigned short* __restrict__ xb,
    const unsigned short* __restrict__ w1t, const unsigned short* __restrict__ w2t,
    const float* __restrict__ b1, const float* __restrict__ b2,
    const int* __restrict__ offsets, const int* __restrict__ counts,
    const int* __restrict__ perm, const float* __restrict__ gatev,
    unsigned short* __restrict__ ybuf, float* __restrict__ out) {
  __shared__ __align__(16) unsigned char smem[32768];   // xa: c 0..15; ha: c 0..31 (aliased)

  // XCD-affinity swizzle (2080 = 8*260, bijective)
  int bid = (int)(blockIdx.x & 7) * 260 + (int)(blockIdx.x >> 3);
  int slot0 = bid * 64;
  if (slot0 >= offsets[NE]) return;
  int e = 0;
#pragma unroll
  for (int i = 1; i < NE; ++i)
    if (slot0 >= offsets[i]) e = i;
  int cnt = counts[e];
  int local0 = slot0 - offsets[e];
  int nvalid = min(64, cnt - local0);

  int t = threadIdx.x;
  int w = t >> 6;
  int l = t & 63;
  int quad = l >> 4;
  int l15 = l & 15;

  int pvl = 0;
  float gvl = 0.f;
  if (YB) {
    uint4 v[4];
    if (l < nvalid) {
      pvl = perm[slot0 + l];
      gvl = gatev[slot0 + l];
      const uint4* rowp = (const uint4*)(xb + (size_t)pvl * DIM);
#pragma unroll
      for (int cc = 0; cc < 4; ++cc) v[cc] = rowp[w * 4 + cc];
    } else {
#pragma unroll
      for (int cc = 0; cc < 4; ++cc) { v[cc].x = 0u; v[cc].y = 0u; v[cc].z = 0u; v[cc].w = 0u; }
    }
#pragma unroll
    for (int cc = 0; cc < 4; ++cc)
      *(uint4*)(smem + LDSA(w * 4 + cc, l, 0)) = v[cc];
  } else {
    unsigned pk[16];
    if (l < nvalid) {
      pvl = perm[slot0 + l];
      gvl = gatev[slot0 + l];
      const float* src = x + (size_t)pvl * DIM + w * 32;
#pragma unroll
      for (int q = 0; q < 8; ++q) {
        float4 vv = ((const float4*)src)[q];
        pk[q * 2 + 0] = (unsigned)f2bf(vv.x) | ((unsigned)f2bf(vv.y) << 16);
        pk[q * 2 + 1] = (unsigned)f2bf(vv.z) | ((unsigned)f2bf(vv.w) << 16);
      }
    } else {
#pragma unroll
      for (int q = 0; q < 16; ++q) pk[q] = 0u;
    }
#pragma unroll
    for (int cc = 0; cc < 4; ++cc) {
      uint4 u;
      u.x = pk[cc * 4 + 0]; u.y = pk[cc * 4 + 1]; u.z = pk[cc * 4 + 2]; u.w = pk[cc * 4 + 3];
      *(uint4*)(smem + LDSA(w * 4 + cc, l, 0)) = u;
    }
  }

  const unsigned short* w1e = w1t + (size_t)e * DIM * HID;
  bf16x8 w1f[4][4];
#pragma unroll
  for (int kc = 0; kc < 4; ++kc)
#pragma unroll
    for (int jt = 0; jt < 4; ++jt)
      w1f[kc][jt] = *(const bf16x8*)(w1e + kc * 8192 + (w * 64 + jt * 16 + l15) * 32 + quad * 8);

  __syncthreads();   // (1) xa staged

  f32x4 acc[4][4];
#pragma unroll
  for (int a = 0; a < 4; ++a)
#pragma unroll
    for (int bb = 0; bb < 4; ++bb) {
      f32x4 z = {0.f, 0.f, 0.f, 0.f};
      acc[a][bb] = z;
    }
#pragma unroll
  for (int kc = 0; kc < 4; ++kc) {
    bf16x8 af[4];
#pragma unroll
    for (int rt = 0; rt < 4; ++rt)
      af[rt] = *(const bf16x8*)(smem + LDSA(kc * 4 + quad, rt * 16 + l15, 0));
#pragma unroll
    for (int rt = 0; rt < 4; ++rt)
#pragma unroll
      for (int jt = 0; jt < 4; ++jt)
        acc[rt][jt] = __builtin_amdgcn_mfma_f32_16x16x32_bf16(af[rt], w1f[kc][jt], acc[rt][jt], 0, 0, 0);
  }

  const unsigned short* w2e = w2t + (size_t)e * HID * DIM;
  bf16x8 w2f[8][2];
#pragma unroll
  for (int hc = 0; hc < 8; ++hc)
#pragma unroll
    for (int jt = 0; jt < 2; ++jt)
      w2f[hc][jt] = *(const bf16x8*)(w2e + hc * 4096 + (w * 32 + jt * 16 + l15) * 32 + quad * 8);

  __syncthreads();   // (2) all xa reads done; ha may overwrite

  // GEMM1 epilogue: lane's 4 jt-values are h = w*64 + 4*l15 + {0..3} -> one b64 write
  {
    float4 b1v = *(const float4*)(b1 + e * HID + w * 64 + 4 * l15);
    int c = w * 8 + (l15 >> 1);
    int byte = (l15 & 1) * 8;
#pragma unroll
    for (int rt = 0; rt < 4; ++rt) {
#pragma unroll
      for (int r = 0; r < 4; ++r) {
        int tokrow = rt * 16 + quad * 4 + r;
        float v0 = acc[rt][0][r] + b1v.x; v0 = v0 > 0.f ? v0 : 0.f;
        float v1 = acc[rt][1][r] + b1v.y; v1 = v1 > 0.f ? v1 : 0.f;
        float v2 = acc[rt][2][r] + b1v.z; v2 = v2 > 0.f ? v2 : 0.f;
        float v3 = acc[rt][3][r] + b1v.w; v3 = v3 > 0.f ? v3 : 0.f;
        uint2 u;
        u.x = (unsigned)f2bf(v0) | ((unsigned)f2bf(v1) << 16);
        u.y = (unsigned)f2bf(v2) | ((unsigned)f2bf(v3) << 16);
        *(uint2*)(smem + LDSA(c, tokrow, byte)) = u;
      }
    }
  }
  __syncthreads();   // (3) ha ready

  f32x4 accc[4][2];
#pragma unroll
  for (int a = 0; a < 4; ++a)
#pragma unroll
    for (int bb = 0; bb < 2; ++bb) {
      f32x4 z = {0.f, 0.f, 0.f, 0.f};
      accc[a][bb] = z;
    }
#pragma unroll
  for (int hc = 0; hc < 8; ++hc) {
    bf16x8 ah[4];
#pragma unroll
    for (int rt = 0; rt < 4; ++rt)
      ah[rt] = *(const bf16x8*)(smem + LDSA(hc * 4 + quad, rt * 16 + l15, 0));
#pragma unroll
    for (int rt = 0; rt < 4; ++rt)
#pragma unroll
      for (int jt = 0; jt < 2; ++jt)
        accc[rt][jt] = __builtin_amdgcn_mfma_f32_16x16x32_bf16(ah[rt], w2f[hc][jt], accc[rt][jt], 0, 0, 0);
  }

  // GEMM2 epilogue: lane's 2 jt-values are d = w*32 + 2*l15 + {0,1} -> one 4B store.
  // Slot-addressed ybuf: block writes rows slot0..slot0+63 (contiguous stream).
  int dbase = w * 32;
  float2 b2v = *(const float2*)(b2 + e * DIM + dbase + 2 * l15);
#pragma unroll
  for (int rt = 0; rt < 4; ++rt) {
#pragma unroll
    for (int r = 0; r < 4; ++r) {
      int tokrow = rt * 16 + quad * 4 + r;
      int pv = __shfl(pvl, tokrow);     // all lanes participate
      float g = __shfl(gvl, tokrow);
      if (tokrow < nvalid) {
        float y0 = g * (accc[rt][0][r] + b2v.x);
        float y1 = g * (accc[rt][1][r] + b2v.y);
        if (YB) {
          unsigned pack = (unsigned)f2bf(y0) | ((unsigned)f2bf(y1) << 16);
          *(unsigned*)(ybuf + (size_t)(slot0 + tokrow) * DIM + dbase + 2 * l15) = pack;
        } else {
          float* orow = out + (size_t)pv * DIM + dbase + 2 * l15;
          atomicAdd(&orow[0], y0);
          atomicAdd(&orow[1], y1);
        }
      }
    }
  }
}

// ---------------- combine: out[n] = ybuf[inv[2n]] + ybuf[inv[2n+1]] ----------------
// 32 tokens/block (2 unrolled iterations) to halve block count / launch+tail overhead.
__global__ __launch_bounds__(256) void k_combine(const unsigned short* __restrict__ ybuf,
                                                 const int* __restrict__ inv,
                                                 float* __restrict__ out) {
  int t = threadIdx.x;
  int lane = t & 15;
#pragma unroll
  for (int j = 0; j < 2; ++j) {
    int n = blockIdx.x * 32 + j * 16 + (t >> 4);
    int2 iv = ((const int2*)inv)[n];
    uint4 a = *((const uint4*)(ybuf + (size_t)iv.x * DIM) + lane);
    uint4 b = *((const uint4*)(ybuf + (size_t)iv.y * DIM) + lane);
    unsigned av[4] = {a.x, a.y, a.z, a.w}, bv[4] = {b.x, b.y, b.z, b.w};
    float r[8];
#pragma unroll
    for (int q = 0; q < 4; ++q) {
      r[q * 2 + 0] = bf2f(av[q] & 0xffffu) + bf2f(bv[q] & 0xffffu);
      r[q * 2 + 1] = bf2f(av[q] >> 16) + bf2f(bv[q] >> 16);
    }
    float* orow = out + (size_t)n * DIM + lane * 8;
    float4 w0 = {r[0], r[1], r[2], r[3]}, w1 = {r[4], r[5], r[6], r[7]};
    ((float4*)orow)[0] = w0;
    ((float4*)orow)[1] = w1;
  }
}

extern "C" void kernel_launch(void* const* d_in, const int* in_sizes, int n_in,
                              void* d_out, int out_size, void* d_ws, size_t ws_size,
                              hipStream_t stream) {
  const float* x  = (const float*)d_in[0];
  const float* W1 = (const float*)d_in[1];
  const float* b1 = (const float*)d_in[2];
  const float* W2 = (const float*)d_in[3];
  const float* b2 = (const float*)d_in[4];
  const float* Wr = (const float*)d_in[5];
  const float* br = (const float*)d_in[6];
  float* out = (float*)d_out;

  char* ws = (char*)d_ws;
  int*   counts   = (int*)(ws + 0);         // 32 i
  int*   offsets  = (int*)(ws + 128);       // 33 i
  int*   top_idx  = (int*)(ws + 1024);      // 131072 i -> 525312
  float* top_val  = (float*)(ws + 525312);  // 131072 f -> 1049600
  int*   perm     = (int*)(ws + 1049600);   // 133120 i -> 1582080
  float* gatev    = (float*)(ws + 1582080); // 133120 f -> 2114560
  int*   inv      = (int*)(ws + 2114560);   // 131072 i -> 2638848
  int*   histbuf  = (int*)(ws + 2638848);   // 1024*32 i -> 2769920
  float* impbuf   = (float*)(ws + 2769920); // 1024*32 f -> 2900992
  unsigned short* w1t = (unsigned short*)(ws + 2900992);  // 2 MB -> 4998144
  unsigned short* w2t = (unsigned short*)(ws + 4998144);  // 2 MB -> 7095296
  unsigned short* ybuf = (unsigned short*)(ws + 7095296); // 34078720 -> 41174016
  const size_t NEEDED = 41174016;
  bool use_ybuf = ws_size >= NEEDED;

  // bf16 copy of x in the head of `out` (16.8 MB): written by k_front's router
  // blocks, consumed by k_expert<1>, fully overwritten by k_combine afterwards.
  unsigned short* xb = (unsigned short*)out;

  if (use_ybuf) {
    hipLaunchKernelGGL(k_front, dim3(1536), dim3(256), 0, stream, x, W1, W2, Wr, br,
                       top_idx, top_val, xb, w1t, w2t, histbuf, impbuf);
    hipLaunchKernelGGL(k_scatter2, dim3(512), dim3(256), 0, stream, top_idx, top_val,
                       histbuf, impbuf, perm, gatev, inv, offsets, counts,
                       out + (size_t)N_TOK * DIM);
    hipLaunchKernelGGL((k_expert<1>), dim3(2080), dim3(256), 0, stream, x, xb, w1t, w2t,
                       b1, b2, offsets, counts, perm, gatev, ybuf, out);
    hipLaunchKernelGGL(k_combine, dim3(2048), dim3(256), 0, stream, ybuf, inv, out);
  } else {
    hipLaunchKernelGGL(k_front, dim3(1536), dim3(256), 0, stream, x, W1, W2, Wr, br,
                       top_idx, top_val, xb, w1t, w2t, histbuf, impbuf);
    hipLaunchKernelGGL(k_scatter2, dim3(512), dim3(256), 0, stream, top_idx, top_val,
                       histbuf, impbuf, perm, gatev, inv, offsets, counts,
                       out + (size_t)N_TOK * DIM);
    hipLaunchKernelGGL(k_zero_out, dim3(4096), dim3(256), 0, stream, out);
    hipLaunchKernelGGL((k_expert<0>), dim3(2080), dim3(256), 0, stream, x,
                       (const unsigned short*)0, w1t, w2t, b1, b2, offsets, counts,
                       perm, gatev, (unsigned short*)0, out);
  }
}